// Round 1
// baseline (178.331 us; speedup 1.0000x reference)
//
#include <hip/hip_runtime.h>
#include <math.h>

// N = 2^21 exactly
#define NSITES 2097152
#define NMASK  (NSITES - 1)

__device__ __forceinline__ float elu1(float v) {
    return v > 0.0f ? v : expm1f(v);
}

// (t_a x t_b) . t_c for the tetrahedron vectors:
// 0 if any index repeats, else +/- 4/sqrt(27) by permutation parity.
__device__ __forceinline__ float tp_val(int a, int b, int c) {
    if (a == b || b == c || a == c) return 0.0f;
    int inv = (a > b) + (a > c) + (b > c);
    int d   = 6 - a - b - c;                 // missing index
    float base = (d & 1) ? 0.76980035891950105f : -0.76980035891950105f;
    return (inv & 1) ? -base : base;
}

__global__ __launch_bounds__(256) void su2_cnn_kernel(
    const int*   __restrict__ x,
    const float* __restrict__ kdot,   // [3][5]
    const float* __restrict__ ktri,   // [3][5][5]
    const float* __restrict__ k0,     // [5][6][3]
    const float* __restrict__ bias,   // [3]
    const float* __restrict__ dw,     // [3]
    float*       __restrict__ out)
{
    __shared__ int   xs[265];        // x[base .. base+264]
    __shared__ float tp[64];         // triple-product table
    __shared__ float anti2[3][10];   // 2*(ktri[f][j][k]-ktri[f][k][j]), j<k pairs
    __shared__ float ys[260][7];     // 260 sites x 6 features, pad to 7 (bank)
    __shared__ float red[4];

    const int tid  = threadIdx.x;
    const int base = blockIdx.x << 8;

    // ---- stage x (265 values, wrap via &NMASK) ----
    xs[tid] = x[(base + tid) & NMASK];
    if (tid < 9) xs[256 + tid] = x[(base + 256 + tid) & NMASK];

    // ---- triple-product table ----
    if (tid < 64) {
        tp[tid] = tp_val(tid >> 4, (tid >> 2) & 3, tid & 3);
    }

    // ---- antisymmetrized triple kernel, folded factor 2 ----
    if (tid < 3) {
        const int f = tid;
        int p = 0;
        #pragma unroll
        for (int j = 0; j < 5; ++j)
            #pragma unroll
            for (int k = j + 1; k < 5; ++k) {
                anti2[f][p] = 2.0f * (ktri[f * 25 + j * 5 + k] - ktri[f * 25 + k * 5 + j]);
                ++p;
            }
    }
    __syncthreads();

    // ---- per-site features y[s][0..5] for s in [0,260) ----
    for (int s = tid; s < 260; s += 256) {
        const int a = xs[s];
        int nb[5];
        #pragma unroll
        for (int k = 0; k < 5; ++k) nb[k] = xs[s + 1 + k];

        // dot features
        float yd0 = 0.f, yd1 = 0.f, yd2 = 0.f;
        #pragma unroll
        for (int k = 0; k < 5; ++k) {
            const float sm = (a == nb[k]) ? 1.0f : -1.0f;
            yd0 = fmaf(kdot[0 * 5 + k], sm, yd0);
            yd1 = fmaf(kdot[1 * 5 + k], sm, yd1);
            yd2 = fmaf(kdot[2 * 5 + k], sm, yd2);
        }

        // triple features: sum over j<k pairs of anti2 * TP[a, nb[j], nb[k]]
        float yt0 = 0.f, yt1 = 0.f, yt2 = 0.f;
        {
            int p = 0;
            #pragma unroll
            for (int j = 0; j < 5; ++j)
                #pragma unroll
                for (int k = j + 1; k < 5; ++k) {
                    const float t = tp[(a << 4) + (nb[j] << 2) + nb[k]];
                    yt0 = fmaf(anti2[0][p], t, yt0);
                    yt1 = fmaf(anti2[1][p], t, yt1);
                    yt2 = fmaf(anti2[2][p], t, yt2);
                    ++p;
                }
        }

        ys[s][0] = elu1(yd0);
        ys[s][1] = elu1(yd1);
        ys[s][2] = elu1(yd2);
        ys[s][3] = elu1(yt0);
        ys[s][4] = elu1(yt1);
        ys[s][5] = elu1(yt2);
    }
    __syncthreads();

    // ---- conv: z[m,f] = bias[f] + sum_{j,c} k0[j,c,f] * ys[m+j][c] ----
    float acc0 = bias[0], acc1 = bias[1], acc2 = bias[2];
    #pragma unroll
    for (int j = 0; j < 5; ++j) {
        #pragma unroll
        for (int c = 0; c < 6; ++c) {
            const float yv = ys[tid + j][c];
            const int kb = (j * 6 + c) * 3;
            acc0 = fmaf(k0[kb + 0], yv, acc0);
            acc1 = fmaf(k0[kb + 1], yv, acc1);
            acc2 = fmaf(k0[kb + 2], yv, acc2);
        }
    }

    // elu, fold dense_w
    float partial = elu1(acc0) * dw[0] + elu1(acc1) * dw[1] + elu1(acc2) * dw[2];

    // ---- block reduction (wave shuffle + LDS) ----
    #pragma unroll
    for (int off = 32; off > 0; off >>= 1)
        partial += __shfl_down(partial, off, 64);

    const int wave = tid >> 6;
    const int lane = tid & 63;
    if (lane == 0) red[wave] = partial;
    __syncthreads();

    if (tid == 0) {
        const float s = (red[0] + red[1]) + (red[2] + red[3]);
        atomicAdd(out, s * (1.0f / (float)NSITES));
    }
}

extern "C" void kernel_launch(void* const* d_in, const int* in_sizes, int n_in,
                              void* d_out, int out_size, void* d_ws, size_t ws_size,
                              hipStream_t stream) {
    const int*   x    = (const int*)  d_in[0];
    const float* kdot = (const float*)d_in[1];
    const float* ktri = (const float*)d_in[2];
    const float* k0   = (const float*)d_in[3];
    const float* bias = (const float*)d_in[4];
    const float* dw   = (const float*)d_in[5];
    float* out = (float*)d_out;

    // d_out is poisoned before every launch; we accumulate into it.
    hipMemsetAsync(out, 0, sizeof(float), stream);

    su2_cnn_kernel<<<NSITES / 256, 256, 0, stream>>>(x, kdot, ktri, k0, bias, dw, out);
}

// Round 2
// 101.226 us; speedup vs baseline: 1.7617x; 1.7617x over previous
//
#include <hip/hip_runtime.h>
#include <math.h>

// N = 2^21 exactly
#define NSITES 2097152
#define NMASK  (NSITES - 1)
#define SITES_PER_BLOCK 1024
#define SITES_PER_THREAD 4
#define NBLOCKS (NSITES / SITES_PER_BLOCK)   // 2048

__device__ __forceinline__ float elu1(float v) {
    // exp(v)-1 for v<=0: abs err ~1e-7, far under threshold; v_exp_f32 path.
    return v > 0.0f ? v : __expf(v) - 1.0f;
}

// (t_a x t_b) . t_c for tetrahedron vectors: 0 if any repeat, else +/- 4/sqrt(27).
__device__ __forceinline__ float tp_val(int a, int b, int c) {
    if (a == b || b == c || a == c) return 0.0f;
    int inv = (a > b) + (a > c) + (b > c);
    int d   = 6 - a - b - c;                 // missing index
    float base = (d & 1) ? 0.76980035891950105f : -0.76980035891950105f;
    return (inv & 1) ? -base : base;
}

__global__ __launch_bounds__(256) void su2_cnn_kernel(
    const int*   __restrict__ x,
    const float* __restrict__ kdot,   // [3][5]
    const float* __restrict__ ktri,   // [3][5][5]
    const float* __restrict__ k0,     // [5][6][3]
    const float* __restrict__ bias,   // [3]
    const float* __restrict__ dw,     // [3]
    float*       __restrict__ out)
{
    __shared__ int   xs[1036];          // x[base .. base+1032]
    __shared__ float ys[6][1032];       // SoA features, sites 0..1027 used
    __shared__ float tp[64];            // triple-product table
    __shared__ float anti2[3][10];      // 2*(ktri[f][j][k]-ktri[f][k][j]), j<k
    __shared__ float red[4];

    const int tid  = threadIdx.x;
    const int base = blockIdx.x * SITES_PER_BLOCK;

    // ---- stage x: 1024 via int4, 9 halo scalar ----
    {
        const int4 xv = *reinterpret_cast<const int4*>(x + base + 4 * tid);
        *reinterpret_cast<int4*>(&xs[4 * tid]) = xv;
        if (tid < 9) xs[1024 + tid] = x[(base + 1024 + tid) & NMASK];
    }

    // ---- triple-product table ----
    if (tid < 64) tp[tid] = tp_val(tid >> 4, (tid >> 2) & 3, tid & 3);

    // ---- antisymmetrized triple kernel (x2 folded) ----
    if (tid < 3) {
        const int f = tid;
        int p = 0;
        #pragma unroll
        for (int j = 0; j < 5; ++j)
            #pragma unroll
            for (int k = j + 1; k < 5; ++k) {
                anti2[f][p] = 2.0f * (ktri[f * 25 + j * 5 + k] - ktri[f * 25 + k * 5 + j]);
                ++p;
            }
    }
    __syncthreads();

    // ---- features for sites 0..1027 ----
    for (int s = tid; s < SITES_PER_BLOCK + 4; s += 256) {
        const int a = xs[s];
        int nb[5];
        #pragma unroll
        for (int k = 0; k < 5; ++k) nb[k] = xs[s + 1 + k];

        float yd0 = 0.f, yd1 = 0.f, yd2 = 0.f;
        #pragma unroll
        for (int k = 0; k < 5; ++k) {
            const float sm = (a == nb[k]) ? 1.0f : -1.0f;
            yd0 = fmaf(kdot[0 * 5 + k], sm, yd0);
            yd1 = fmaf(kdot[1 * 5 + k], sm, yd1);
            yd2 = fmaf(kdot[2 * 5 + k], sm, yd2);
        }

        float yt0 = 0.f, yt1 = 0.f, yt2 = 0.f;
        {
            int p = 0;
            #pragma unroll
            for (int j = 0; j < 5; ++j)
                #pragma unroll
                for (int k = j + 1; k < 5; ++k) {
                    const float t = tp[(a << 4) + (nb[j] << 2) + nb[k]];
                    yt0 = fmaf(anti2[0][p], t, yt0);
                    yt1 = fmaf(anti2[1][p], t, yt1);
                    yt2 = fmaf(anti2[2][p], t, yt2);
                    ++p;
                }
        }

        ys[0][s] = elu1(yd0);
        ys[1][s] = elu1(yd1);
        ys[2][s] = elu1(yd2);
        ys[3][s] = elu1(yt0);
        ys[4][s] = elu1(yt1);
        ys[5][s] = elu1(yt2);
    }
    __syncthreads();

    // ---- conv: 4 outputs per thread, m = 4*tid + o ----
    const int m0 = 4 * tid;
    float yv[6][8];
    #pragma unroll
    for (int c = 0; c < 6; ++c) {
        const float4 a = *reinterpret_cast<const float4*>(&ys[c][m0]);
        const float4 b = *reinterpret_cast<const float4*>(&ys[c][m0 + 4]);
        yv[c][0] = a.x; yv[c][1] = a.y; yv[c][2] = a.z; yv[c][3] = a.w;
        yv[c][4] = b.x; yv[c][5] = b.y; yv[c][6] = b.z; yv[c][7] = b.w;
    }

    const float b0 = bias[0], b1 = bias[1], b2 = bias[2];
    float acc0[4], acc1[4], acc2[4];
    #pragma unroll
    for (int o = 0; o < 4; ++o) { acc0[o] = b0; acc1[o] = b1; acc2[o] = b2; }

    #pragma unroll
    for (int j = 0; j < 5; ++j) {
        #pragma unroll
        for (int c = 0; c < 6; ++c) {
            const int kb = (j * 6 + c) * 3;
            const float w0 = k0[kb + 0], w1 = k0[kb + 1], w2 = k0[kb + 2];
            #pragma unroll
            for (int o = 0; o < 4; ++o) {
                const float yvv = yv[c][o + j];
                acc0[o] = fmaf(w0, yvv, acc0[o]);
                acc1[o] = fmaf(w1, yvv, acc1[o]);
                acc2[o] = fmaf(w2, yvv, acc2[o]);
            }
        }
    }

    const float d0 = dw[0], d1 = dw[1], d2 = dw[2];
    float partial = 0.0f;
    #pragma unroll
    for (int o = 0; o < 4; ++o)
        partial += elu1(acc0[o]) * d0 + elu1(acc1[o]) * d1 + elu1(acc2[o]) * d2;

    // ---- block reduction ----
    #pragma unroll
    for (int off = 32; off > 0; off >>= 1)
        partial += __shfl_down(partial, off, 64);

    const int wave = tid >> 6;
    if ((tid & 63) == 0) red[wave] = partial;
    __syncthreads();

    if (tid == 0) {
        const float s = (red[0] + red[1]) + (red[2] + red[3]);
        atomicAdd(out, s * (1.0f / (float)NSITES));
    }
}

extern "C" void kernel_launch(void* const* d_in, const int* in_sizes, int n_in,
                              void* d_out, int out_size, void* d_ws, size_t ws_size,
                              hipStream_t stream) {
    const int*   x    = (const int*)  d_in[0];
    const float* kdot = (const float*)d_in[1];
    const float* ktri = (const float*)d_in[2];
    const float* k0   = (const float*)d_in[3];
    const float* bias = (const float*)d_in[4];
    const float* dw   = (const float*)d_in[5];
    float* out = (float*)d_out;

    hipMemsetAsync(out, 0, sizeof(float), stream);
    su2_cnn_kernel<<<NBLOCKS, 256, 0, stream>>>(x, kdot, ktri, k0, bias, dw, out);
}

// Round 3
// 87.123 us; speedup vs baseline: 2.0469x; 1.1619x over previous
//
#include <hip/hip_runtime.h>
#include <math.h>

// N = 2^21 exactly
#define NSITES 2097152
#define NMASK  (NSITES - 1)

__device__ __forceinline__ float elu1(float v) {
    // exp(v)-1 for v<=0 via v_exp_f32; abs err ~1e-7 << 2.2e-4 threshold.
    return v > 0.0f ? v : __expf(v) - 1.0f;
}

// (t_a x t_b) . t_c for tetrahedron vectors: 0 if any repeat, else +/- 4/sqrt(27).
__device__ __forceinline__ float tp_val(int a, int b, int c) {
    if (a == b || b == c || a == c) return 0.0f;
    int inv = (a > b) + (a > c) + (b > c);
    int d   = 6 - a - b - c;                 // missing index
    float base = (d & 1) ? 0.76980035891950105f : -0.76980035891950105f;
    return (inv & 1) ? -base : base;
}

// ---------------------------------------------------------------------------
// Kernel 1: tabulate post-elu features for all 4096 codes of (x[s..s+5]).
//   tab4[code] = (elu(yd0), elu(yd1), elu(yd2), elu(yt0))
//   tab2[code] = (elu(yt1), elu(yt2))
// ---------------------------------------------------------------------------
__global__ __launch_bounds__(256) void build_tables(
    const float* __restrict__ kdot,   // [3][5]
    const float* __restrict__ ktri,   // [3][5][5]
    float*       __restrict__ ws)
{
    float4* tab4 = reinterpret_cast<float4*>(ws);
    float2* tab2 = reinterpret_cast<float2*>(ws + 16384);   // after 4096 float4

    const int code = blockIdx.x * 256 + threadIdx.x;        // 0..4095
    const int a = code & 3;
    int nb[5];
    #pragma unroll
    for (int k = 0; k < 5; ++k) nb[k] = (code >> (2 + 2 * k)) & 3;

    float yd0 = 0.f, yd1 = 0.f, yd2 = 0.f;
    #pragma unroll
    for (int k = 0; k < 5; ++k) {
        const float sm = (a == nb[k]) ? 1.0f : -1.0f;
        yd0 = fmaf(kdot[0 * 5 + k], sm, yd0);
        yd1 = fmaf(kdot[1 * 5 + k], sm, yd1);
        yd2 = fmaf(kdot[2 * 5 + k], sm, yd2);
    }

    float yt0 = 0.f, yt1 = 0.f, yt2 = 0.f;
    #pragma unroll
    for (int j = 0; j < 5; ++j)
        #pragma unroll
        for (int k = j + 1; k < 5; ++k) {
            const float t = tp_val(a, nb[j], nb[k]);
            const float a0 = 2.0f * (ktri[0 * 25 + j * 5 + k] - ktri[0 * 25 + k * 5 + j]);
            const float a1 = 2.0f * (ktri[1 * 25 + j * 5 + k] - ktri[1 * 25 + k * 5 + j]);
            const float a2 = 2.0f * (ktri[2 * 25 + j * 5 + k] - ktri[2 * 25 + k * 5 + j]);
            yt0 = fmaf(a0, t, yt0);
            yt1 = fmaf(a1, t, yt1);
            yt2 = fmaf(a2, t, yt2);
        }

    tab4[code] = make_float4(elu1(yd0), elu1(yd1), elu1(yd2), elu1(yt0));
    tab2[code] = make_float2(elu1(yt1), elu1(yt2));
}

// ---------------------------------------------------------------------------
// Kernel 2: conv + elu + mean + dense, 8 outputs/thread, table-gather features.
// Grid 256 blocks x 1024 threads = exactly 1 block/CU.
// ---------------------------------------------------------------------------
__global__ __launch_bounds__(1024) void conv_kernel(
    const int*   __restrict__ x,
    const float* __restrict__ k0,     // [5][6][3]
    const float* __restrict__ bias,   // [3]
    const float* __restrict__ dw,     // [3]
    const float* __restrict__ ws,
    float*       __restrict__ out)
{
    __shared__ float4 s4[4096];       // 64 KB
    __shared__ float2 s2[4096];       // 32 KB
    __shared__ float  red[16];

    const int tid = threadIdx.x;

    // ---- stage tables into LDS (coalesced) ----
    {
        const float4* tab4 = reinterpret_cast<const float4*>(ws);
        const float2* tab2 = reinterpret_cast<const float2*>(ws + 16384);
        #pragma unroll
        for (int i = 0; i < 4; ++i) {
            const int idx = tid + 1024 * i;
            s4[idx] = tab4[idx];
            s2[idx] = tab2[idx];
        }
    }
    __syncthreads();

    // ---- load x[m0 .. m0+16] via wrap-safe aligned int4 chunks ----
    const int m0 = (blockIdx.x * 1024 + tid) * 8;
    int xv[20];
    #pragma unroll
    for (int c = 0; c < 5; ++c) {
        const int4 v = *reinterpret_cast<const int4*>(x + ((m0 + 4 * c) & NMASK));
        xv[4 * c + 0] = v.x; xv[4 * c + 1] = v.y;
        xv[4 * c + 2] = v.z; xv[4 * c + 3] = v.w;
    }

    // pack 17 2-bit values into a 34-bit code word
    unsigned long long code = 0ull;
    #pragma unroll
    for (int j = 0; j < 17; ++j)
        code |= (unsigned long long)(unsigned)xv[j] << (2 * j);

    // ---- conv: z[m0+o, f] = bias[f] + sum_{j,c} k0[j,c,f] * y[m0+o+j, c] ----
    const float b0 = bias[0], b1 = bias[1], b2 = bias[2];
    float acc[8][3];
    #pragma unroll
    for (int o = 0; o < 8; ++o) { acc[o][0] = b0; acc[o][1] = b1; acc[o][2] = b2; }

    #pragma unroll
    for (int i = 0; i < 12; ++i) {                 // site m0+i
        const int idx = (int)((code >> (2 * i)) & 0xFFFull);
        const float4 a4 = s4[idx];
        const float2 a2 = s2[idx];
        const float y[6] = { a4.x, a4.y, a4.z, a4.w, a2.x, a2.y };
        #pragma unroll
        for (int j = 0; j < 5; ++j) {              // kernel tap
            const int o = i - j;                   // output this site feeds
            if (o >= 0 && o < 8) {
                #pragma unroll
                for (int c = 0; c < 6; ++c) {
                    const int kb = (j * 6 + c) * 3;
                    acc[o][0] = fmaf(k0[kb + 0], y[c], acc[o][0]);
                    acc[o][1] = fmaf(k0[kb + 1], y[c], acc[o][1]);
                    acc[o][2] = fmaf(k0[kb + 2], y[c], acc[o][2]);
                }
            }
        }
    }

    // ---- elu, dense, per-thread partial ----
    const float d0 = dw[0], d1 = dw[1], d2 = dw[2];
    float partial = 0.0f;
    #pragma unroll
    for (int o = 0; o < 8; ++o)
        partial += elu1(acc[o][0]) * d0 + elu1(acc[o][1]) * d1 + elu1(acc[o][2]) * d2;

    // ---- block reduction: wave shuffle -> LDS -> thread 0 ----
    #pragma unroll
    for (int off = 32; off > 0; off >>= 1)
        partial += __shfl_down(partial, off, 64);

    if ((tid & 63) == 0) red[tid >> 6] = partial;
    __syncthreads();

    if (tid == 0) {
        float s = 0.0f;
        #pragma unroll
        for (int w = 0; w < 16; ++w) s += red[w];
        atomicAdd(out, s * (1.0f / (float)NSITES));
    }
}

extern "C" void kernel_launch(void* const* d_in, const int* in_sizes, int n_in,
                              void* d_out, int out_size, void* d_ws, size_t ws_size,
                              hipStream_t stream) {
    const int*   x    = (const int*)  d_in[0];
    const float* kdot = (const float*)d_in[1];
    const float* ktri = (const float*)d_in[2];
    const float* k0   = (const float*)d_in[3];
    const float* bias = (const float*)d_in[4];
    const float* dw   = (const float*)d_in[5];
    float* out = (float*)d_out;
    float* ws  = (float*)d_ws;

    hipMemsetAsync(out, 0, sizeof(float), stream);
    build_tables<<<16, 256, 0, stream>>>(kdot, ktri, ws);
    conv_kernel<<<NSITES / 8192, 1024, 0, stream>>>(x, k0, bias, dw, ws, out);
}

// Round 4
// 84.798 us; speedup vs baseline: 2.1030x; 1.0274x over previous
//
#include <hip/hip_runtime.h>
#include <math.h>

// N = 2^21 exactly
#define NSITES 2097152
#define NMASK  (NSITES - 1)

__device__ __forceinline__ float elu1(float v) {
    // exp(v)-1 for v<=0 via v_exp_f32; abs err ~1e-7 << 2.2e-4 threshold.
    return v > 0.0f ? v : __expf(v) - 1.0f;
}

// (t_a x t_b) . t_c for tetrahedron vectors: 0 if any repeat, else +/- 4/sqrt(27).
__device__ __forceinline__ float tp_val(int a, int b, int c) {
    if (a == b || b == c || a == c) return 0.0f;
    int inv = (a > b) + (a > c) + (b > c);
    int d   = 6 - a - b - c;                 // missing index
    float base = (d & 1) ? 0.76980035891950105f : -0.76980035891950105f;
    return (inv & 1) ? -base : base;
}

// ---------------------------------------------------------------------------
// Single fused kernel: per-block feature-table build (4096 codes, post-elu)
// + conv + elu + mean + dense.  256 blocks x 1024 threads, 8 outputs/thread.
// ---------------------------------------------------------------------------
__global__ __launch_bounds__(1024) void su2_fused_kernel(
    const int*   __restrict__ x,
    const float* __restrict__ kdot,   // [3][5]
    const float* __restrict__ ktri,   // [3][5][5]
    const float* __restrict__ k0,     // [5][6][3]
    const float* __restrict__ bias,   // [3]
    const float* __restrict__ dw,     // [3]
    float*       __restrict__ out)
{
    __shared__ float4 s4[4096];       // feats 0..3, 64 KB
    __shared__ float2 s2[4096];       // feats 4..5, 32 KB
    __shared__ float  tp[64];         // triple-product table
    __shared__ float  red[16];

    const int tid = threadIdx.x;

    // ---- issue x loads early (17 sites needed; 5 aligned int4 = 20) ----
    const int m0 = (blockIdx.x * 1024 + tid) * 8;
    int4 xraw[5];
    #pragma unroll
    for (int c = 0; c < 5; ++c)
        xraw[c] = *reinterpret_cast<const int4*>(x + ((m0 + 4 * c) & NMASK));

    // ---- tp table ----
    if (tid < 64) tp[tid] = tp_val(tid >> 4, (tid >> 2) & 3, tid & 3);

    // ---- uniform weights -> SGPRs (scalar loads; all offsets constant) ----
    float kd[3][5];
    #pragma unroll
    for (int f = 0; f < 3; ++f)
        #pragma unroll
        for (int k = 0; k < 5; ++k) kd[f][k] = kdot[f * 5 + k];

    float an[3][10];
    #pragma unroll
    for (int f = 0; f < 3; ++f) {
        int p = 0;
        #pragma unroll
        for (int j = 0; j < 5; ++j)
            #pragma unroll
            for (int k = j + 1; k < 5; ++k) {
                an[f][p] = 2.0f * (ktri[f * 25 + j * 5 + k] - ktri[f * 25 + k * 5 + j]);
                ++p;
            }
    }
    __syncthreads();

    // ---- build post-elu feature table: 4 codes per thread ----
    #pragma unroll
    for (int i = 0; i < 4; ++i) {
        const int code = tid + 1024 * i;
        const int a = code & 3;
        int nb[5];
        #pragma unroll
        for (int k = 0; k < 5; ++k) nb[k] = (code >> (2 + 2 * k)) & 3;

        float yd0 = 0.f, yd1 = 0.f, yd2 = 0.f;
        #pragma unroll
        for (int k = 0; k < 5; ++k) {
            const float sm = (a == nb[k]) ? 1.0f : -1.0f;
            yd0 = fmaf(kd[0][k], sm, yd0);
            yd1 = fmaf(kd[1][k], sm, yd1);
            yd2 = fmaf(kd[2][k], sm, yd2);
        }

        float yt0 = 0.f, yt1 = 0.f, yt2 = 0.f;
        {
            int p = 0;
            #pragma unroll
            for (int j = 0; j < 5; ++j)
                #pragma unroll
                for (int k = j + 1; k < 5; ++k) {
                    const float t = tp[(a << 4) + (nb[j] << 2) + nb[k]];
                    yt0 = fmaf(an[0][p], t, yt0);
                    yt1 = fmaf(an[1][p], t, yt1);
                    yt2 = fmaf(an[2][p], t, yt2);
                    ++p;
                }
        }

        s4[code] = make_float4(elu1(yd0), elu1(yd1), elu1(yd2), elu1(yt0));
        s2[code] = make_float2(elu1(yt1), elu1(yt2));
    }
    __syncthreads();

    // ---- pack 17 2-bit x values into a 34-bit code word ----
    int xv[20];
    #pragma unroll
    for (int c = 0; c < 5; ++c) {
        xv[4 * c + 0] = xraw[c].x; xv[4 * c + 1] = xraw[c].y;
        xv[4 * c + 2] = xraw[c].z; xv[4 * c + 3] = xraw[c].w;
    }
    unsigned long long code = 0ull;
    #pragma unroll
    for (int j = 0; j < 17; ++j)
        code |= (unsigned long long)(unsigned)xv[j] << (2 * j);

    // ---- conv: z[m0+o, f] = bias[f] + sum_{j,c} k0[j,c,f] * y[m0+o+j, c] ----
    const float b0 = bias[0], b1 = bias[1], b2 = bias[2];
    float acc[8][3];
    #pragma unroll
    for (int o = 0; o < 8; ++o) { acc[o][0] = b0; acc[o][1] = b1; acc[o][2] = b2; }

    #pragma unroll
    for (int i = 0; i < 12; ++i) {                 // site m0+i
        const int idx = (int)((code >> (2 * i)) & 0xFFFull);
        const float4 a4 = s4[idx];
        const float2 a2 = s2[idx];
        const float y[6] = { a4.x, a4.y, a4.z, a4.w, a2.x, a2.y };
        #pragma unroll
        for (int j = 0; j < 5; ++j) {              // kernel tap
            const int o = i - j;                   // output this site feeds
            if (o >= 0 && o < 8) {
                #pragma unroll
                for (int c = 0; c < 6; ++c) {
                    const int kb = (j * 6 + c) * 3;
                    acc[o][0] = fmaf(k0[kb + 0], y[c], acc[o][0]);
                    acc[o][1] = fmaf(k0[kb + 1], y[c], acc[o][1]);
                    acc[o][2] = fmaf(k0[kb + 2], y[c], acc[o][2]);
                }
            }
        }
    }

    // ---- elu, dense, per-thread partial ----
    const float d0 = dw[0], d1 = dw[1], d2 = dw[2];
    float partial = 0.0f;
    #pragma unroll
    for (int o = 0; o < 8; ++o)
        partial += elu1(acc[o][0]) * d0 + elu1(acc[o][1]) * d1 + elu1(acc[o][2]) * d2;

    // ---- block reduction: wave shuffle -> LDS -> thread 0 ----
    #pragma unroll
    for (int off = 32; off > 0; off >>= 1)
        partial += __shfl_down(partial, off, 64);

    if ((tid & 63) == 0) red[tid >> 6] = partial;
    __syncthreads();

    if (tid == 0) {
        float s = 0.0f;
        #pragma unroll
        for (int w = 0; w < 16; ++w) s += red[w];
        atomicAdd(out, s * (1.0f / (float)NSITES));
    }
}

extern "C" void kernel_launch(void* const* d_in, const int* in_sizes, int n_in,
                              void* d_out, int out_size, void* d_ws, size_t ws_size,
                              hipStream_t stream) {
    const int*   x    = (const int*)  d_in[0];
    const float* kdot = (const float*)d_in[1];
    const float* ktri = (const float*)d_in[2];
    const float* k0   = (const float*)d_in[3];
    const float* bias = (const float*)d_in[4];
    const float* dw   = (const float*)d_in[5];
    float* out = (float*)d_out;

    hipMemsetAsync(out, 0, sizeof(float), stream);
    su2_fused_kernel<<<NSITES / 8192, 1024, 0, stream>>>(x, kdot, ktri, k0, bias, dw, out);
}